// Round 1
// 1384.570 us; speedup vs baseline: 2.0781x; 2.0781x over previous
//
#include <hip/hip_runtime.h>
#include <cmath>

#ifndef M_PI
#define M_PI 3.14159265358979323846
#endif

#define K_CHEB 48
#define A_CHEB 0.05
#define B_CHEB 14.0
#define PS_S 7
#define PS_Q 6

typedef __attribute__((ext_vector_type(8))) short bhalf8;
typedef __attribute__((ext_vector_type(16))) float f32x16;

struct PSArg {
  float mid, invhalf;
  float a[PS_Q + 1][PS_S];   // a[q][r]
};

// ---------- bf16 split helpers ----------

// packed RNE f32->bf16: lo16 = bf16(a), hi16 = bf16(b). One VALU op.
__device__ __forceinline__ unsigned cvt_pk_bf16(float a, float b) {
  unsigned r;
  asm("v_cvt_pk_bf16_f32 %0, %1, %2" : "=v"(r) : "v"(a), "v"(b));
  return r;
}

// split 4 floats into bf16 hi/lo pairs and store 8B each to LDS.
// off must be a multiple of 4 (8-byte alignment).
__device__ __forceinline__ void split4_store(short* __restrict__ Xh, short* __restrict__ Xl,
                                             int off, float v0, float v1, float v2, float v3) {
  unsigned h01 = cvt_pk_bf16(v0, v1);
  unsigned h23 = cvt_pk_bf16(v2, v3);
  float r0 = v0 - __uint_as_float(h01 << 16);
  float r1 = v1 - __uint_as_float(h01 & 0xffff0000u);
  float r2 = v2 - __uint_as_float(h23 << 16);
  float r3 = v3 - __uint_as_float(h23 & 0xffff0000u);
  unsigned l01 = cvt_pk_bf16(r0, r1);
  unsigned l23 = cvt_pk_bf16(r2, r3);
  *(uint2*)(Xh + off) = make_uint2(h01, h23);
  *(uint2*)(Xl + off) = make_uint2(l01, l23);
}

// ---------- generic fp32 LDS helpers (small single-matrix kernels) ----------

__device__ __forceinline__ void stage64(const float* __restrict__ g, float* __restrict__ s, int tid) {
#pragma unroll
  for (int r = 0; r < 4; r++) {
    int idx = tid + 256 * r;
    *(float4*)(s + 4 * idx) = *(const float4*)(g + 4 * idx);
  }
}

__device__ __forceinline__ void store_tile(float* __restrict__ S, int r0, int c0, const float t[16]) {
#pragma unroll
  for (int i = 0; i < 4; i++)
    *(float4*)(S + (r0 + i) * 64 + c0) = *(const float4*)(&t[4 * i]);
}

// C = A^T B (== A*B for symmetric A). Row-wise float4 LDS reads.
__device__ __forceinline__ void gemm_tile_sym(const float* __restrict__ A, const float* __restrict__ B,
                                              int r0, int c0, float t[16]) {
#pragma unroll
  for (int i = 0; i < 16; i++) t[i] = 0.f;
#pragma unroll 4
  for (int k = 0; k < 64; k += 4) {
    float a[16], b[16];
#pragma unroll
    for (int kk = 0; kk < 4; kk++) {
      *(float4*)(&a[4 * kk]) = *(const float4*)(A + (k + kk) * 64 + r0);
      *(float4*)(&b[4 * kk]) = *(const float4*)(B + (k + kk) * 64 + c0);
    }
#pragma unroll
    for (int kk = 0; kk < 4; kk++)
#pragma unroll
      for (int i = 0; i < 4; i++)
#pragma unroll
        for (int j = 0; j < 4; j++)
          t[4 * i + j] += a[4 * kk + i] * b[4 * kk + j];
  }
}

// ---------- batch mean ----------

__global__ __launch_bounds__(256) void reduce_mean8(const float* __restrict__ data,
                                                    float* __restrict__ part) {
  const size_t base = (size_t)blockIdx.x * 8 * 4096;
  const int tid = threadIdx.x;
#pragma unroll
  for (int r = 0; r < 4; r++) {
    int idx = tid + 256 * r;
    float4 s = make_float4(0.f, 0.f, 0.f, 0.f);
#pragma unroll
    for (int m = 0; m < 8; m++) {
      float4 v = *(const float4*)(data + base + (size_t)m * 4096 + 4 * idx);
      s.x += v.x; s.y += v.y; s.z += v.z; s.w += v.w;
    }
    *(float4*)(part + (size_t)blockIdx.x * 4096 + 4 * idx) = s;
  }
}

// 64 blocks; block handles 64 columns, 4-way split over the parts dimension.
__global__ __launch_bounds__(256) void reduce_cols(const float* __restrict__ part,
                                                   float* __restrict__ outv,
                                                   int nparts, float scale) {
  __shared__ float s[3][64];
  const int jj = threadIdx.x & 63, gg = threadIdx.x >> 6;
  const int j = (blockIdx.x << 6) + jj;
  float sum = 0.f;
  for (int g = gg; g < nparts; g += 4)
    sum += part[(size_t)g * 4096 + j];
  if (gg) s[gg - 1][jj] = sum;
  __syncthreads();
  if (gg == 0) outv[j] = (sum + s[0][jj] + s[1][jj] + s[2][jj]) * scale;
}

// ---------- the hot kernel: per-batch logm via MFMA + Paterson-Stockmeyer ----------
//
// Per 64x64 matrix: W = Mi*D*Mi (2 products), T_r = 2*What*T_{r-1}-T_{r-2} r=2..7
// (6 products, T_1..T_6 kept element-wise in regs), then matrix-Clenshaw in
// Y = T_7 with matrix coefficients G_q = sum_r a[q][r] T_r (6 products).
// All products: fp32 split to bf16 hi/lo, 3 MFMA (hi*hi + hi*lo + lo*hi).
// B-operand is stored TRANSPOSED in LDS; A-operand fragments live in registers.
//
// v2 changes vs previous session:
//  - dg f32x16 -> int dsel compare (-16 VGPRs): kills scratch spills (was 490 MB
//    excess FETCH/dispatch from spill reloads on the critical path)
//  - v_cvt_pk_bf16_f32 packed split (RNE, same rounding as manual path): ~140
//    fewer VALU ops per phase and far fewer live temps
//  - 4-buffer LDS (sM, sA, sB0, sB1; 72 KB dynamic): ONE barrier per product
//    instead of two (write target never aliases same-phase read source)

#define LDX 72   // padded row stride (elements); 144 B = 9*16 B -> 16B-aligned frags
#define MAT (64 * LDX)

__device__ __forceinline__ void load_afrags(const short* __restrict__ Xh, const short* __restrict__ Xl,
                                            int aoff, bhalf8 ah[4], bhalf8 al[4]) {
#pragma unroll
  for (int kb = 0; kb < 4; kb++) {
    ah[kb] = *(const bhalf8*)(Xh + aoff + 16 * kb);
    al[kb] = *(const bhalf8*)(Xl + aoff + 16 * kb);
  }
}

__device__ __forceinline__ f32x16 prod3(const bhalf8 ah[4], const bhalf8 al[4],
                                        const short* __restrict__ Bh, const short* __restrict__ Bl,
                                        int boff) {
  f32x16 acc;
#pragma unroll
  for (int t = 0; t < 16; t++) acc[t] = 0.f;
#pragma unroll
  for (int kb = 0; kb < 4; kb++) {
    bhalf8 bh = *(const bhalf8*)(Bh + boff + 16 * kb);
    bhalf8 bl = *(const bhalf8*)(Bl + boff + 16 * kb);
    acc = __builtin_amdgcn_mfma_f32_32x32x16_bf16(ah[kb], bh, acc, 0, 0, 0);
    acc = __builtin_amdgcn_mfma_f32_32x32x16_bf16(ah[kb], bl, acc, 0, 0, 0);
    acc = __builtin_amdgcn_mfma_f32_32x32x16_bf16(al[kb], bh, acc, 0, 0, 0);
  }
  return acc;
}

// write v^T (hi/lo bf16) into X: X[n][m] = v[m][n]; n = bcol, m = 32R+8g+4*half+t
__device__ __forceinline__ void tstore16(short* __restrict__ Xh, short* __restrict__ Xl,
                                         int bcol, int R, int half, const f32x16 v) {
#pragma unroll
  for (int g = 0; g < 4; g++) {
    int off = bcol * LDX + 32 * R + 8 * g + 4 * half;
    split4_store(Xh, Xl, off, v[4 * g + 0], v[4 * g + 1], v[4 * g + 2], v[4 * g + 3]);
  }
}

// stage a row-major 64x64 fp32 matrix into bf16 hi/lo LDS
__device__ __forceinline__ void stage_split(const float* __restrict__ g64,
                                            short* __restrict__ Xh, short* __restrict__ Xl,
                                            int tid) {
#pragma unroll
  for (int i = 0; i < 4; i++) {
    int idx = tid + 256 * i;
    float4 v = *(const float4*)(g64 + 4 * idx);
    int row = idx >> 4, col = (idx & 15) << 2;
    split4_store(Xh, Xl, row * LDX + col, v.x, v.y, v.z, v.w);
  }
}

__global__ __launch_bounds__(256, 2) void cheb_ps(const float* __restrict__ data,
                                                  const float* __restrict__ Mi,
                                                  float* __restrict__ partial,
                                                  PSArg co) {
  extern __shared__ __align__(16) short smem[];
  short* sMh  = smem;
  short* sMl  = sMh + MAT;
  short* sAh  = sMl + MAT;
  short* sAl  = sAh + MAT;
  short* sB0h = sAl + MAT;
  short* sB0l = sB0h + MAT;
  short* sB1h = sB0l + MAT;
  short* sB1l = sB1h + MAT;

  const int tid = threadIdx.x;
  const int lane = tid & 63, wv = tid >> 6;
  const int R = wv >> 1, C = wv & 1;
  const int ln31 = lane & 31, half = lane >> 5;
  const int aoff = (32 * R + ln31) * LDX + half * 8;   // A-frag element offset (+16*kb)
  const int bcol = 32 * C + ln31;
  const int boff = bcol * LDX + half * 8;              // B-frag element offset (+16*kb)
  // D-layout row of acc element (4g+t) is 32R+8g+4half+t; diagonal when == bcol:
  const int dsel = bcol - 32 * R - 4 * half;           // diag iff 8*g + t == dsel

  // stage Mi (block-constant) as bf16 hi/lo, row-major
  stage_split(Mi, sMh, sMl, tid);

  f32x16 accTm;
#pragma unroll
  for (int t = 0; t < 16; t++) accTm[t] = 0.f;

  bhalf8 ah[4], al[4];
  __syncthreads();

#pragma unroll 1
  for (int m = 0; m < 8; m++) {
    // stage D -> sA row-major (D symmetric). sA's last readers finished phases ago.
    stage_split(data + ((size_t)blockIdx.x * 8 + m) * 4096, sAh, sAl, tid);
    __syncthreads();

    // P1: V = D*Mi  (A=D from sA, B=Mi from sM) -> sB0
    load_afrags(sAh, sAl, aoff, ah, al);
    f32x16 acc = prod3(ah, al, sMh, sMl, boff);
    tstore16(sB0h, sB0l, bcol, R, half, acc);
    __syncthreads();

    // P2: W = Mi*V  (A=Mi from sM, B=V from sB0) -> What -> sA
    load_afrags(sMh, sMl, aoff, ah, al);
    acc = prod3(ah, al, sB0h, sB0l, boff);
    f32x16 T1;
#pragma unroll
    for (int g = 0; g < 4; g++)
#pragma unroll
      for (int t = 0; t < 4; t++) {
        float a = acc[4 * g + t];
        if (8 * g + t == dsel) a -= co.mid;
        T1[4 * g + t] = a * co.invhalf;
      }
    tstore16(sAh, sAl, bcol, R, half, T1);
    __syncthreads();

    // A := What (read sA row-major; == What^T, symmetric to ~1e-4 - washed out by sym() later)
    load_afrags(sAh, sAl, aoff, ah, al);

    f32x16 T2, T3, T4, T5, T6;
    // r=2: B = What (sA) -> sB0
    acc = prod3(ah, al, sAh, sAl, boff);
#pragma unroll
    for (int g = 0; g < 4; g++)
#pragma unroll
      for (int t = 0; t < 4; t++)
        T2[4 * g + t] = 2.f * acc[4 * g + t] - ((8 * g + t == dsel) ? 1.f : 0.f);
    tstore16(sB0h, sB0l, bcol, R, half, T2);
    __syncthreads();

    // r=3: B = T2 (sB0) -> sB1
    acc = prod3(ah, al, sB0h, sB0l, boff);
#pragma unroll
    for (int t = 0; t < 16; t++) T3[t] = 2.f * acc[t] - T1[t];
    tstore16(sB1h, sB1l, bcol, R, half, T3);
    __syncthreads();

    // r=4: B = T3 (sB1) -> sB0
    acc = prod3(ah, al, sB1h, sB1l, boff);
#pragma unroll
    for (int t = 0; t < 16; t++) T4[t] = 2.f * acc[t] - T2[t];
    tstore16(sB0h, sB0l, bcol, R, half, T4);
    __syncthreads();

    // r=5: B = T4 (sB0) -> sB1
    acc = prod3(ah, al, sB0h, sB0l, boff);
#pragma unroll
    for (int t = 0; t < 16; t++) T5[t] = 2.f * acc[t] - T3[t];
    tstore16(sB1h, sB1l, bcol, R, half, T5);
    __syncthreads();

    // r=6: B = T5 (sB1) -> sB0
    acc = prod3(ah, al, sB1h, sB1l, boff);
#pragma unroll
    for (int t = 0; t < 16; t++) T6[t] = 2.f * acc[t] - T4[t];
    tstore16(sB1h == sB1h ? sB0h : sB0h, sB0l, bcol, R, half, T6);
    __syncthreads();

    // r=7: B = T6 (sB0) -> Y -> sA  (sA readers done at r=2; barriers since)
    acc = prod3(ah, al, sB0h, sB0l, boff);
    f32x16 Y7;
#pragma unroll
    for (int t = 0; t < 16; t++) Y7[t] = 2.f * acc[t] - T5[t];
    tstore16(sAh, sAl, bcol, R, half, Y7);
    __syncthreads();

    load_afrags(sAh, sAl, aoff, ah, al);             // A := Y
    // Clenshaw init: bq1 = G6 (elementwise) -> sB1 ; bq2 = 0
    f32x16 bq1, bq2;
#pragma unroll
    for (int g = 0; g < 4; g++)
#pragma unroll
      for (int t = 0; t < 4; t++) {
        int i = 4 * g + t;
        float v = co.a[6][1] * T1[i] + co.a[6][2] * T2[i] + co.a[6][3] * T3[i]
                + co.a[6][4] * T4[i] + co.a[6][5] * T5[i] + co.a[6][6] * T6[i];
        if (8 * g + t == dsel) v += co.a[6][0];
        bq1[i] = v; bq2[i] = 0.f;
      }
    tstore16(sB1h, sB1l, bcol, R, half, bq1);
    __syncthreads();

    // q = 5..1: read b_{q+1} from alternating buffer, write b_q to the other
#pragma unroll
    for (int q = 5; q >= 1; q--) {
      const short* rh = (q & 1) ? sB1h : sB0h;
      const short* rl = (q & 1) ? sB1l : sB0l;
      short* wh = (q & 1) ? sB0h : sB1h;
      short* wl = (q & 1) ? sB0l : sB1l;
      acc = prod3(ah, al, rh, rl, boff);
      f32x16 nb;
#pragma unroll
      for (int g = 0; g < 4; g++)
#pragma unroll
        for (int t = 0; t < 4; t++) {
          int i = 4 * g + t;
          float gq = co.a[q][1] * T1[i] + co.a[q][2] * T2[i] + co.a[q][3] * T3[i]
                   + co.a[q][4] * T4[i] + co.a[q][5] * T5[i] + co.a[q][6] * T6[i];
          if (8 * g + t == dsel) gq += co.a[q][0];
          nb[i] = gq + 2.f * acc[i] - bq2[i];
        }
      bq2 = bq1; bq1 = nb;
      tstore16(wh, wl, bcol, R, half, bq1);
      __syncthreads();
    }

    // final: Y*b1, B = b1 (sB0; q=1 wrote sB0). No store -> no barrier needed:
    // the next stage writes sA, which has no outstanding readers.
    acc = prod3(ah, al, sB0h, sB0l, boff);
#pragma unroll
    for (int g = 0; g < 4; g++)
#pragma unroll
      for (int t = 0; t < 4; t++) {
        int i = 4 * g + t;
        float g0 = co.a[0][1] * T1[i] + co.a[0][2] * T2[i] + co.a[0][3] * T3[i]
                 + co.a[0][4] * T4[i] + co.a[0][5] * T5[i] + co.a[0][6] * T6[i];
        if (8 * g + t == dsel) g0 += co.a[0][0];
        accTm[i] += g0 + acc[i] - bq2[i];
      }
  }

  // write block-partial sum of logs (D-layout scatter; once per block)
  float* pp = partial + (size_t)blockIdx.x * 4096;
#pragma unroll
  for (int g = 0; g < 4; g++)
#pragma unroll
    for (int t = 0; t < 4; t++)
      pp[(32 * R + 8 * g + 4 * half + t) * 64 + bcol] = accTm[4 * g + t];
}

// ---------- single-matrix sqrt/invsqrt via binomial series ----------

__global__ __launch_bounds__(256) void invsqrt_series(const float* __restrict__ Min,
                                                      float* __restrict__ MiOut,
                                                      float* __restrict__ MsOut) {
  __shared__ float sM[4096], sE[4096], sE2[4096], sE3[4096];
  __shared__ float csh;
  const int tid = threadIdx.x;
  const int r0 = (tid >> 4) << 2, c0 = (tid & 15) << 2;

  stage64(Min, sM, tid);
  __syncthreads();
  if (tid == 0) {
    float s = 0.f;
    for (int i = 0; i < 64; i++) s += sM[i * 64 + i];
    csh = s * (1.f / 64.f);
  }
  __syncthreads();
  const float invc = 1.f / csh;
  for (int idx = tid; idx < 4096; idx += 256) {
    int r = idx >> 6, c = idx & 63;
    sE[idx] = 0.5f * (sM[idx] + sM[c * 64 + r]) * invc - ((r == c) ? 1.f : 0.f);
  }
  __syncthreads();

  float t[16];
  gemm_tile_sym(sE, sE, r0, c0, t);  store_tile(sE2, r0, c0, t); __syncthreads();
  gemm_tile_sym(sE2, sE, r0, c0, t); store_tile(sE3, r0, c0, t); __syncthreads();
  gemm_tile_sym(sE2, sE2, r0, c0, t); store_tile(sM, r0, c0, t); __syncthreads();
  float t5[16];
  gemm_tile_sym(sE2, sE3, r0, c0, t5);

  const float sc = sqrtf(csh), rsc = 1.f / sc;
#pragma unroll
  for (int i = 0; i < 4; i++)
#pragma unroll
    for (int j = 0; j < 4; j++) {
      int off = (r0 + i) * 64 + (c0 + j);
      float d = ((r0 + i) == (c0 + j)) ? 1.f : 0.f;
      float e = sE[off], e2 = sE2[off], e3 = sE3[off], e4 = sM[off], e5 = t5[4 * i + j];
      float mi = (d - 0.5f * e + 0.375f * e2 - 0.3125f * e3 + 0.2734375f * e4 - 0.24609375f * e5) * rsc;
      float ms = (d + 0.5f * e - 0.125f * e2 + 0.0625f * e3 - 0.0390625f * e4 + 0.02734375f * e5) * sc;
      MiOut[off] = mi;
      MsOut[off] = ms;
    }
}

// ---------- Taylor-8 expm ----------

__device__ void taylor_expm8(const float* __restrict__ sA, float* __restrict__ sR,
                             int tid, int r0, int c0, float postscale) {
  for (int idx = tid; idx < 4096; idx += 256) {
    int r = idx >> 6, c = idx & 63;
    sR[idx] = ((r == c) ? 1.f : 0.f) + sA[idx] * 0.125f;
  }
  __syncthreads();
  float t[16];
#pragma unroll 1
  for (int k = 7; k >= 1; k--) {
    gemm_tile_sym(sA, sR, r0, c0, t);
    __syncthreads();
    const float inv = 1.f / (float)k;
    const float fin = (k == 1) ? postscale : 1.f;
#pragma unroll
    for (int i = 0; i < 4; i++)
#pragma unroll
      for (int j = 0; j < 4; j++) {
        int off = (r0 + i) * 64 + (c0 + j);
        float d = ((r0 + i) == (c0 + j)) ? 1.f : 0.f;
        sR[off] = (d + t[4 * i + j] * inv) * fin;
      }
    __syncthreads();
  }
}

__global__ __launch_bounds__(256) void expm_update(const float* __restrict__ Tin,
                                                   const float* __restrict__ Msin,
                                                   float* __restrict__ Mout) {
  __shared__ float sA[4096], sR[4096], sB[4096];
  __shared__ float mush;
  const int tid = threadIdx.x;
  const int r0 = (tid >> 4) << 2, c0 = (tid & 15) << 2;

  stage64(Tin, sB, tid);
  __syncthreads();
  if (tid == 0) {
    float s = 0.f;
    for (int i = 0; i < 64; i++) s += sB[i * 64 + i];
    mush = s * (1.f / 64.f);
  }
  __syncthreads();
  const float mu = mush;
  for (int idx = tid; idx < 4096; idx += 256) {
    int r = idx >> 6, c = idx & 63;
    sA[idx] = 0.5f * (sB[idx] + sB[c * 64 + r]) - ((r == c) ? mu : 0.f);
  }
  __syncthreads();
  taylor_expm8(sA, sR, tid, r0, c0, expf(mu));

  stage64(Msin, sB, tid);
  __syncthreads();
  float t[16];
  gemm_tile_sym(sR, sB, r0, c0, t);
  store_tile(sA, r0, c0, t);
  __syncthreads();
  gemm_tile_sym(sB, sA, r0, c0, t);
#pragma unroll
  for (int i = 0; i < 4; i++)
    *(float4*)(Mout + (r0 + i) * 64 + c0) = *(const float4*)(&t[4 * i]);
}

__global__ __launch_bounds__(256) void bias_expm_P(const float* __restrict__ bias,
                                                   const float* __restrict__ Gin,
                                                   float* __restrict__ Pout) {
  __shared__ float sA[4096], sR[4096], sB[4096];
  const int tid = threadIdx.x;
  const int r0 = (tid >> 4) << 2, c0 = (tid & 15) << 2;

  stage64(bias, sB, tid);
  __syncthreads();
  for (int idx = tid; idx < 4096; idx += 256) {
    int r = idx >> 6, c = idx & 63;
    sA[idx] = 0.0625f * (sB[idx] + sB[c * 64 + r]);
  }
  __syncthreads();
  taylor_expm8(sA, sR, tid, r0, c0, 1.f);

  float t[16];
  gemm_tile_sym(sR, sR, r0, c0, t);
  store_tile(sB, r0, c0, t);
  __syncthreads();
  gemm_tile_sym(sB, sB, r0, c0, t);
  store_tile(sR, r0, c0, t);
  stage64(Gin, sA, tid);
  __syncthreads();
  gemm_tile_sym(sR, sA, r0, c0, t);
#pragma unroll
  for (int i = 0; i < 4; i++)
    *(float4*)(Pout + (r0 + i) * 64 + c0) = *(const float4*)(&t[4 * i]);
}

__global__ __launch_bounds__(256) void final_out(const float* __restrict__ data,
                                                 const float* __restrict__ Pin,
                                                 float* __restrict__ out) {
  __shared__ float sPT[4096], sD[4096], sT[4096];
  const int tid = threadIdx.x;
  const int r0 = (tid >> 4) << 2, c0 = (tid & 15) << 2;

  for (int idx = tid; idx < 4096; idx += 256) {
    int r = idx >> 6, c = idx & 63;
    sPT[c * 64 + r] = Pin[idx];
  }
  __syncthreads();
  float t[16];
#pragma unroll 1
  for (int m = 0; m < 8; m++) {
    size_t b = (size_t)blockIdx.x * 8 + m;
    stage64(data + b * 4096, sD, tid);
    __syncthreads();
    gemm_tile_sym(sD, sPT, r0, c0, t);
    store_tile(sT, r0, c0, t);
    __syncthreads();
    gemm_tile_sym(sPT, sT, r0, c0, t);
    float* ob = out + b * 4096;
#pragma unroll
    for (int i = 0; i < 4; i++)
      *(float4*)(ob + (r0 + i) * 64 + c0) = *(const float4*)(&t[4 * i]);
    __syncthreads();
  }
}

// ---------- launch ----------

extern "C" void kernel_launch(void* const* d_in, const int* in_sizes, int n_in,
                              void* d_out, int out_size, void* d_ws, size_t ws_size,
                              hipStream_t stream) {
  const float* data = (const float*)d_in[0];
  const float* bias = (const float*)d_in[1];
  float* out = (float*)d_out;

  float* part = out;                 // 16 MB partial scratch inside d_out
  float* M  = (float*)d_ws;
  float* Mi = M + 4096;
  float* Ms = Mi + 4096;
  float* Tm = Ms + 4096;
  float* G  = Tm + 4096;
  float* P  = G + 4096;

  // 72 KB dynamic LDS for cheb_ps (2 blocks/CU: 144 KB of 160 KB)
  static bool attr_done = false;
  if (!attr_done) {
    hipFuncSetAttribute(reinterpret_cast<const void*>(cheb_ps),
                        hipFuncAttributeMaxDynamicSharedMemorySize,
                        8 * MAT * (int)sizeof(short));
    attr_done = true;
  }
  const int lds_bytes = 8 * MAT * (int)sizeof(short);

  // Chebyshev coefficients of log on [a,b], then exact Paterson-Stockmeyer
  // re-factoring: sum_k c_k T_k = sum_q [sum_r a_qr T_r] T_q(T_s), s=7, Q=6.
  PSArg co;
  {
    const double a = A_CHEB, b = B_CHEB;
    const int N = 256;
    double c[64] = {0};
    for (int j = 0; j <= K_CHEB; j++) {
      double s = 0.0;
      for (int k = 0; k < N; k++) {
        double th = M_PI * (k + 0.5) / N;
        double x = 0.5 * (a + b) + 0.5 * (b - a) * std::cos(th);
        s += std::log(x) * std::cos(j * th);
      }
      c[j] = 2.0 * s / N;
    }
    c[0] *= 0.5;                     // plain sum convention
    double aa[PS_Q + 1][PS_S] = {};
    for (int q = PS_Q; q >= 1; --q) {
      for (int r = PS_S - 1; r >= 1; --r) {
        int k = q * PS_S + r;
        double av = 2.0 * c[k];
        aa[q][r] = av;
        c[k] -= av * 0.5;            // -> 0
        c[q * PS_S - r] -= av * 0.5; // reflection T_r*T_qs = (T_qs+r + T_qs-r)/2
      }
      aa[q][0] = c[q * PS_S];
      c[q * PS_S] = 0.0;
    }
    for (int r = 0; r < PS_S; r++) aa[0][r] = c[r];
    co.mid = (float)(0.5 * (a + b));
    co.invhalf = (float)(2.0 / (b - a));
    for (int q = 0; q <= PS_Q; q++)
      for (int r = 0; r < PS_S; r++) co.a[q][r] = (float)aa[q][r];
  }

  reduce_mean8<<<1024, 256, 0, stream>>>(data, part);
  reduce_cols<<<64, 256, 0, stream>>>(part, M, 1024, 1.f / 8192.f);

  for (int it = 0; it < 3; ++it) {
    invsqrt_series<<<1, 256, 0, stream>>>(M, Mi, Ms);
    cheb_ps<<<1024, 256, lds_bytes, stream>>>(data, Mi, part, co);
    reduce_cols<<<64, 256, 0, stream>>>(part, Tm, 1024, 1.f / 8192.f);
    expm_update<<<1, 256, 0, stream>>>(Tm, Ms, M);
  }

  invsqrt_series<<<1, 256, 0, stream>>>(M, G, Ms);
  bias_expm_P<<<1, 256, 0, stream>>>(bias, G, P);
  final_out<<<1024, 256, 0, stream>>>(data, P, out);
}